// Round 1
// 1086.445 us; speedup vs baseline: 1.3658x; 1.3658x over previous
//
#include <hip/hip_runtime.h>
#include <hip/hip_bf16.h>

// Problem constants
#define NB 4
#define NT 256
#define NU 128
#define DENC 512
#define DPRED 640
#define NH 640
#define NV 1025
#define NVP 1088      // V padded to 68 tiles of 16 -> uniform 17 tiles per wave
#define NTILES 68
#define JT 17         // tiles per wave (68 / 4 waves)

typedef __attribute__((ext_vector_type(8))) short short8;
typedef __attribute__((ext_vector_type(4))) float f32x4;

__device__ __forceinline__ unsigned short bfu(float a) {
    union { __hip_bfloat16 h; unsigned short u; } cv;
    cv.h = __float2bfloat16(a);
    return cv.u;
}

__device__ __forceinline__ unsigned pk2(float a, float b) {
    union { __hip_bfloat162 h; unsigned u; } cv;
    cv.h = __float22bfloat162_rn(float2{a, b});
    return cv.u;
}

__device__ __forceinline__ short8 pack_relu(f32x4 x, f32x4 y) {
    union { short8 s; unsigned u[4]; } r;
    r.u[0] = pk2(fmaxf(x[0], 0.f), fmaxf(x[1], 0.f));
    r.u[1] = pk2(fmaxf(x[2], 0.f), fmaxf(x[3], 0.f));
    r.u[2] = pk2(fmaxf(y[0], 0.f), fmaxf(y[1], 0.f));
    r.u[3] = pk2(fmaxf(y[2], 0.f), fmaxf(y[3], 0.f));
    return r.s;
}

// W_out fp32 [1025][640] -> bf16 [1088][640] zero-padded; bias -> [1088], pads = -1e30
__global__ __launch_bounds__(256) void prep_kernel(const float* __restrict__ Wo,
                                                   const float* __restrict__ bo,
                                                   unsigned short* __restrict__ Wb,
                                                   float* __restrict__ biasp) {
    int idx = blockIdx.x * 256 + threadIdx.x;
    if (idx < NVP * NH) {
        int v = idx / NH;
        Wb[idx] = (v < NV) ? bfu(Wo[idx]) : (unsigned short)0;
    }
    if (idx < NVP) biasp[idx] = (idx < NV) ? bo[idx] : -1e30f;
}

// Projection GEMM: out[b*L + l][n] = sum_k X[b][k][l] * W[n][k] + bias[n]
// X: [NB][K][L] fp32 (strided input), W: [640][K], out: [NB*L][640] fp32
// Block: 256 thr, tile M=32 x N=64, K-step 32. bf16 MFMA 16x16x32.
__global__ __launch_bounds__(256) void proj_kernel(const float* __restrict__ X,
                                                   const float* __restrict__ W,
                                                   const float* __restrict__ bias,
                                                   float* __restrict__ out,
                                                   int L, int K) {
    __shared__ unsigned short As[32][40];   // [m][k], +8 pad keeps 16B align, breaks stride
    __shared__ unsigned short Bs[64][40];   // [n][k]
    int tid = threadIdx.x;
    int wave = tid >> 6, lane = tid & 63;
    int col16 = lane & 15, kgrp = lane >> 4;
    int m0 = blockIdx.x * 32;
    int n0 = blockIdx.y * 64;
    int b = m0 / L, l0 = m0 % L;
    const float* Xb = X + (size_t)b * K * L;

    float bv = bias[n0 + wave * 16 + col16];
    f32x4 c0 = {bv, bv, bv, bv};
    f32x4 c1 = c0;

    int ac = tid >> 3;          // k-local 0..31
    int ar = (tid & 7) * 4;     // m-local 0,4,..28
    int bn = tid >> 2;          // n-local 0..63
    int bc = (tid & 3) * 8;     // k-local 0,8,16,24

    for (int k0 = 0; k0 < K; k0 += 32) {
        f32x4 av  = *(const f32x4*)(Xb + (size_t)(k0 + ac) * L + l0 + ar);
        f32x4 bw0 = *(const f32x4*)(W + (size_t)(n0 + bn) * K + k0 + bc);
        f32x4 bw1 = *(const f32x4*)(W + (size_t)(n0 + bn) * K + k0 + bc + 4);
        __syncthreads();   // previous iter's frag reads done before overwrite
        As[ar + 0][ac] = bfu(av[0]);
        As[ar + 1][ac] = bfu(av[1]);
        As[ar + 2][ac] = bfu(av[2]);
        As[ar + 3][ac] = bfu(av[3]);
        unsigned* bsrow = (unsigned*)&Bs[bn][bc];
        bsrow[0] = pk2(bw0[0], bw0[1]);
        bsrow[1] = pk2(bw0[2], bw0[3]);
        bsrow[2] = pk2(bw1[0], bw1[1]);
        bsrow[3] = pk2(bw1[2], bw1[3]);
        __syncthreads();
        short8 a0  = *(const short8*)&As[col16][kgrp * 8];
        short8 a1  = *(const short8*)&As[16 + col16][kgrp * 8];
        short8 bfr = *(const short8*)&Bs[wave * 16 + col16][kgrp * 8];
        c0 = __builtin_amdgcn_mfma_f32_16x16x32_bf16(a0, bfr, c0, 0, 0, 0);
        c1 = __builtin_amdgcn_mfma_f32_16x16x32_bf16(a1, bfr, c1, 0, 0, 0);
    }
    int n = n0 + wave * 16 + col16;
    #pragma unroll
    for (int i = 0; i < 4; ++i) {
        int r0 = kgrp * 4 + i;
        out[(size_t)(m0 + r0) * NH + n]      = c0[i];
        out[(size_t)(m0 + 16 + r0) * NH + n] = c1[i];
    }
}

// Joint kernel v2: one block per (bt, 64-u strip). 4 waves x 17 n-tiles (uniform,
// branch-free main loop). M=64 rows/block halves W_out L2 traffic vs M=32.
// B-fragments register-prefetched one k-step ahead (depth-1 pipeline); no LDS
// staging for W. Accs: 17 tiles x 4 m-groups x f32x4 = 272 regs (VGPR+AGPR).
__global__ __launch_bounds__(256, 1) void joint_kernel(const float* __restrict__ f,
                                                       const float* __restrict__ g,
                                                       const unsigned short* __restrict__ Wb,
                                                       const float* __restrict__ biasp,
                                                       float* __restrict__ out) {
    __shared__ float fs[NH];
    __shared__ float redm[4][64];
    __shared__ float reds[4][64];
    int tid = threadIdx.x;
    int wave = tid >> 6, lane = tid & 63;
    int col16 = lane & 15, kgrp = lane >> 4;
    int bt = blockIdx.x >> 1;          // b*NT + t
    int u0 = (blockIdx.x & 1) * 64;
    int b = bt >> 8;                   // NT = 256

    for (int i = tid; i < NH; i += 256) fs[i] = f[(size_t)bt * NH + i];
    __syncthreads();

    int tstart = wave * JT;
    const unsigned short* wbp = Wb + (size_t)(tstart * 16 + col16) * NH + kgrp * 8;
    const float* gp[4];
    #pragma unroll
    for (int m = 0; m < 4; ++m)
        gp[m] = g + (size_t)(b * NU + u0 + m * 16 + col16) * NH + kgrp * 8;

    f32x4 c[JT][4];
    #pragma unroll
    for (int j = 0; j < JT; ++j) {
        float bv = biasp[(tstart + j) * 16 + col16];
        f32x4 cv = {bv, bv, bv, bv};
        c[j][0] = cv; c[j][1] = cv; c[j][2] = cv; c[j][3] = cv;
    }

    // prologue: B-fragments for k-step 0
    short8 bf[JT];
    #pragma unroll
    for (int j = 0; j < JT; ++j)
        bf[j] = *(const short8*)(wbp + (size_t)j * 16 * NH);

    // main loop, k-steps 0..18 with depth-1 register prefetch of k-step ks+1
    for (int ks = 0; ks < 19; ++ks) {
        int kb = ks * 32 + kgrp * 8;
        f32x4 fa0 = *(const f32x4*)(fs + kb);
        f32x4 fa1 = *(const f32x4*)(fs + kb + 4);
        short8 a[4];
        #pragma unroll
        for (int m = 0; m < 4; ++m) {
            f32x4 g0 = *(const f32x4*)(gp[m] + ks * 32);
            f32x4 g1 = *(const f32x4*)(gp[m] + ks * 32 + 4);
            a[m] = pack_relu(fa0 + g0, fa1 + g1);
        }
        const unsigned short* wk = wbp + (ks + 1) * 32;
        #pragma unroll
        for (int j = 0; j < JT; ++j) {
            short8 bj = bf[j];
            bf[j] = *(const short8*)(wk + (size_t)j * 16 * NH);  // prefetch ks+1
            c[j][0] = __builtin_amdgcn_mfma_f32_16x16x32_bf16(a[0], bj, c[j][0], 0, 0, 0);
            c[j][1] = __builtin_amdgcn_mfma_f32_16x16x32_bf16(a[1], bj, c[j][1], 0, 0, 0);
            c[j][2] = __builtin_amdgcn_mfma_f32_16x16x32_bf16(a[2], bj, c[j][2], 0, 0, 0);
            c[j][3] = __builtin_amdgcn_mfma_f32_16x16x32_bf16(a[3], bj, c[j][3], 0, 0, 0);
        }
    }
    {   // final k-step ks = 19, no prefetch
        int kb = 19 * 32 + kgrp * 8;
        f32x4 fa0 = *(const f32x4*)(fs + kb);
        f32x4 fa1 = *(const f32x4*)(fs + kb + 4);
        short8 a[4];
        #pragma unroll
        for (int m = 0; m < 4; ++m) {
            f32x4 g0 = *(const f32x4*)(gp[m] + 19 * 32);
            f32x4 g1 = *(const f32x4*)(gp[m] + 19 * 32 + 4);
            a[m] = pack_relu(fa0 + g0, fa1 + g1);
        }
        #pragma unroll
        for (int j = 0; j < JT; ++j) {
            c[j][0] = __builtin_amdgcn_mfma_f32_16x16x32_bf16(a[0], bf[j], c[j][0], 0, 0, 0);
            c[j][1] = __builtin_amdgcn_mfma_f32_16x16x32_bf16(a[1], bf[j], c[j][1], 0, 0, 0);
            c[j][2] = __builtin_amdgcn_mfma_f32_16x16x32_bf16(a[2], bf[j], c[j][2], 0, 0, 0);
            c[j][3] = __builtin_amdgcn_mfma_f32_16x16x32_bf16(a[3], bf[j], c[j][3], 0, 0, 0);
        }
    }

    // ---- fused log-softmax epilogue ----
    // C layout: col = n_tile*16 + (lane&15); row = m*16 + (lane>>4)*4 + reg  (m89-verified)
    float mx[4][4], sl[4][4];
    #pragma unroll
    for (int m = 0; m < 4; ++m) {
        #pragma unroll
        for (int i = 0; i < 4; ++i) {
            float v = -3e38f;
            #pragma unroll
            for (int j = 0; j < JT; ++j) v = fmaxf(v, c[j][m][i]);
            #pragma unroll
            for (int d = 1; d < 16; d <<= 1)
                v = fmaxf(v, __shfl_xor(v, d, 64));
            mx[m][i] = v;
        }
    }
    if (col16 == 0) {
        #pragma unroll
        for (int m = 0; m < 4; ++m)
            #pragma unroll
            for (int i = 0; i < 4; ++i)
                redm[wave][m * 16 + kgrp * 4 + i] = mx[m][i];
    }
    __syncthreads();
    #pragma unroll
    for (int m = 0; m < 4; ++m)
        #pragma unroll
        for (int i = 0; i < 4; ++i) {
            int r = m * 16 + kgrp * 4 + i;
            mx[m][i] = fmaxf(fmaxf(redm[0][r], redm[1][r]), fmaxf(redm[2][r], redm[3][r]));
        }
    #pragma unroll
    for (int m = 0; m < 4; ++m) {
        #pragma unroll
        for (int i = 0; i < 4; ++i) {
            float ssum = 0.f;
            #pragma unroll
            for (int j = 0; j < JT; ++j) ssum += __expf(c[j][m][i] - mx[m][i]);
            #pragma unroll
            for (int d = 1; d < 16; d <<= 1)
                ssum += __shfl_xor(ssum, d, 64);
            sl[m][i] = ssum;
        }
    }
    if (col16 == 0) {
        #pragma unroll
        for (int m = 0; m < 4; ++m)
            #pragma unroll
            for (int i = 0; i < 4; ++i)
                reds[wave][m * 16 + kgrp * 4 + i] = sl[m][i];
    }
    __syncthreads();
    #pragma unroll
    for (int m = 0; m < 4; ++m)
        #pragma unroll
        for (int i = 0; i < 4; ++i) {
            int r = m * 16 + kgrp * 4 + i;
            float S = (reds[0][r] + reds[1][r]) + (reds[2][r] + reds[3][r]);
            sl[m][i] = mx[m][i] + __logf(S);   // m + log(sum exp(x-m))
        }

    size_t orow0 = (size_t)bt * NU + u0;
    #pragma unroll
    for (int m = 0; m < 4; ++m) {
        #pragma unroll
        for (int j = 0; j < JT; ++j) {
            int col = (tstart + j) * 16 + col16;
            if (col < NV) {
                #pragma unroll
                for (int i = 0; i < 4; ++i) {
                    size_t row = orow0 + m * 16 + kgrp * 4 + i;
                    out[row * (size_t)NV + col] = c[j][m][i] - sl[m][i];
                }
            }
        }
    }
}

extern "C" void kernel_launch(void* const* d_in, const int* in_sizes, int n_in,
                              void* d_out, int out_size, void* d_ws, size_t ws_size,
                              hipStream_t stream) {
    const float* enc    = (const float*)d_in[0];  // [4][512][256]
    const float* dec    = (const float*)d_in[1];  // [4][640][128]
    const float* W_enc  = (const float*)d_in[2];  // [640][512]
    const float* b_enc  = (const float*)d_in[3];  // [640]
    const float* W_pred = (const float*)d_in[4];  // [640][640]
    const float* b_pred = (const float*)d_in[5];  // [640]
    const float* W_out  = (const float*)d_in[6];  // [1025][640]
    const float* b_out  = (const float*)d_in[7];  // [1025]
    float* out = (float*)d_out;

    char* ws = (char*)d_ws;
    unsigned short* Wb = (unsigned short*)ws;          // 1,392,640 B (bf16 [1088][640])
    float* biasp = (float*)(ws + 1392640);             // 4,352 B
    float* fbuf  = (float*)(ws + 1396992);             // 2,621,440 B ([1024][640] fp32)
    float* gbuf  = (float*)(ws + 4018432);             // 1,310,720 B ([512][640] fp32)

    prep_kernel<<<(NVP * NH + 255) / 256, 256, 0, stream>>>(W_out, b_out, Wb, biasp);
    proj_kernel<<<dim3((NB * NT) / 32, NH / 64), 256, 0, stream>>>(enc, W_enc, b_enc, fbuf, NT, DENC);
    proj_kernel<<<dim3((NB * NU) / 32, NH / 64), 256, 0, stream>>>(dec, W_pred, b_pred, gbuf, NU, DPRED);
    joint_kernel<<<NB * NT * (NU / 64), 256, 0, stream>>>(fbuf, gbuf, Wb, biasp, out);
}